// Round 11
// baseline (417.139 us; speedup 1.0000x reference)
//
#include <hip/hip_runtime.h>

#define NEG_SLOPE 0.2f

static const int B = 4, N = 50000, R = 100000, E = 1600000;
static const int WDEG  = 64;      // dense w-CSR slab per R-row (mean deg 16)
static const int WIDEG = 80;      // dense wi-CSR slab per N-row (mean deg 32)
static const int R2_CAP = 1024;   // distinct t2 rows (expected ~64)
static const int N1_CAP = 4096;   // n1 nodes (expected ~1k)
static const int X2_CAP = 2048;   // x2 edges (expected ~64)

// ---- build_all: blocks [0,G1) gemm1 x->h1 [n][B][32]; rest: both slab CSRs ----
__global__ void build_all(const float* __restrict__ x, const float* __restrict__ W1,
                          float* __restrict__ h1,
                          const int4* __restrict__ w_rows4, const int4* __restrict__ w_cols4,
                          const float4* __restrict__ w_val4,
                          const int4* __restrict__ wi_rows4, const int4* __restrict__ wi_cols4,
                          const float4* __restrict__ wi_val4,
                          int* __restrict__ w_cnt, int2* __restrict__ w_pairsD,
                          int* __restrict__ wi_cnt, int2* __restrict__ wi_pairsD,
                          int e4, int G1) {
    if ((int)blockIdx.x < G1) {
        __shared__ float sW[32 * 32];
        for (int i = threadIdx.x; i < 1024; i += blockDim.x) sW[i] = W1[i];
        __syncthreads();
        int id = blockIdx.x * blockDim.x + threadIdx.x;
        if (id >= N * B) return;
        int n = id >> 2, b = id & 3;
        const float* xr = x + ((size_t)b * N + n) * 32;
        float acc[32];
#pragma unroll
        for (int c = 0; c < 32; ++c) acc[c] = 0.f;
#pragma unroll
        for (int k = 0; k < 32; ++k) {
            float xv = xr[k];
#pragma unroll
            for (int c = 0; c < 32; ++c) acc[c] += xv * sW[k * 32 + c];
        }
        float* o = h1 + ((size_t)n * B + b) * 32;
#pragma unroll
        for (int c = 0; c < 32; ++c) o[c] = acc[c];
        return;
    }
    int blk = blockIdx.x - G1;
#pragma unroll
    for (int k = 0; k < 2; ++k) {
        int i = blk * 512 + k * 256 + threadIdx.x;
        if (i >= e4) continue;
        int4 wr = w_rows4[i];
        int4 wc = w_cols4[i];
        float4 wv = w_val4[i];
        int rr[4] = {wr.x, wr.y, wr.z, wr.w};
        int cc[4] = {wc.x, wc.y, wc.z, wc.w};
        float vv[4] = {wv.x, wv.y, wv.z, wv.w};
#pragma unroll
        for (int j = 0; j < 4; ++j) {
            int pos = atomicAdd(&w_cnt[rr[j]], 1);
            if (pos < WDEG)
                w_pairsD[(size_t)rr[j] * WDEG + pos] =
                    make_int2(cc[j], __float_as_int(vv[j]));
        }
        int4 ir = wi_rows4[i];
        int4 ic = wi_cols4[i];
        float4 iv = wi_val4[i];
        int r2[4] = {ir.x, ir.y, ir.z, ir.w};
        int c2[4] = {ic.x, ic.y, ic.z, ic.w};
        float v2[4] = {iv.x, iv.y, iv.z, iv.w};
#pragma unroll
        for (int j = 0; j < 4; ++j) {
            int pos = atomicAdd(&wi_cnt[r2[j]], 1);
            if (pos < WIDEG)
                wi_pairsD[(size_t)r2[j] * WIDEG + pos] =
                    make_int2(c2[j], __float_as_int(v2[j]));   // raw val (diag1 later)
        }
    }
}

// ---- frontier: ONE block, LDS dedup bitmasks; 3-level backward slice ----
__global__ __launch_bounds__(1024)
void frontier(const int* __restrict__ w_cnt, const int2* __restrict__ w_pairsD,
              const int* __restrict__ wi_cnt, const int2* __restrict__ wi_pairsD,
              int2* __restrict__ x2list, int* __restrict__ r2list,
              int* __restrict__ n1list, int* __restrict__ r1list,
              int* __restrict__ tails /*0=x2 1=r2 2=n1 3=r1*/) {
    __shared__ unsigned mR2[3128];   // 100k bits
    __shared__ unsigned mN1[1568];   // 50k bits
    __shared__ unsigned mR1[3128];
    __shared__ int r2buf[R2_CAP];
    __shared__ int n1buf[N1_CAP];
    __shared__ int cx2, cr2, cn1, cr1;
    int tid = threadIdx.x;
    for (int i = tid; i < 3128; i += 1024) { mR2[i] = 0; mR1[i] = 0; }
    for (int i = tid; i < 1568; i += 1024) mN1[i] = 0;
    if (tid == 0) { cx2 = 0; cr2 = 0; cn1 = 0; cr1 = 0; }
    __syncthreads();

    // level 1: wi rows N-2 / N-1 -> x2 edge list + r2 set
    for (int idx = tid; idx < 2 * WIDEG; idx += 1024) {
        int which = idx / WIDEG;
        int pos = idx - which * WIDEG;
        int row = N - 2 + which;
        int L = wi_cnt[row]; if (L > WIDEG) L = WIDEG;
        if (pos < L) {
            int2 p = wi_pairsD[(size_t)row * WIDEG + pos];
            int col = p.x;
            int q = atomicAdd(&cx2, 1);
            if (q < X2_CAP) x2list[q] = make_int2(col * 2 + which, p.y);
            unsigned bit = 1u << (col & 31);
            unsigned old = atomicOr(&mR2[col >> 5], bit);
            if (!(old & bit)) {
                int t = atomicAdd(&cr2, 1);
                if (t < R2_CAP) r2buf[t] = col;
            }
        }
    }
    __syncthreads();
    int r2c = cr2; if (r2c > R2_CAP) r2c = R2_CAP;

    // level 2: w slabs of r2 rows -> n1 set
    for (int idx = tid; idx < r2c * WDEG; idx += 1024) {
        int i = idx >> 6, pos = idx & 63;
        int row = r2buf[i];
        int L = w_cnt[row]; if (L > WDEG) L = WDEG;
        if (pos < L) {
            int col = w_pairsD[(size_t)row * WDEG + pos].x;
            unsigned bit = 1u << (col & 31);
            unsigned old = atomicOr(&mN1[col >> 5], bit);
            if (!(old & bit)) {
                int t = atomicAdd(&cn1, 1);
                if (t < N1_CAP) n1buf[t] = col;
            }
        }
    }
    __syncthreads();
    int n1c = cn1; if (n1c > N1_CAP) n1c = N1_CAP;

    // level 3: wi slabs of n1 nodes -> r1 set
    for (int idx = tid; idx < n1c * WIDEG; idx += 1024) {
        int i = idx / WIDEG, pos = idx - i * WIDEG;
        int n = n1buf[i];
        int L = wi_cnt[n]; if (L > WIDEG) L = WIDEG;
        if (pos < L) {
            int col = wi_pairsD[(size_t)n * WIDEG + pos].x;
            unsigned bit = 1u << (col & 31);
            unsigned old = atomicOr(&mR1[col >> 5], bit);
            if (!(old & bit)) {
                int t = atomicAdd(&cr1, 1);
                r1list[t] = col;
            }
        }
    }
    __syncthreads();
    for (int t = tid; t < r2c; t += 1024) r2list[t] = r2buf[t];
    for (int t = tid; t < n1c; t += 1024) n1list[t] = n1buf[t];
    if (tid == 0) {
        int x2c = cx2; if (x2c > X2_CAP) x2c = X2_CAP;
        tails[0] = x2c; tails[1] = r2c; tails[2] = n1c; tails[3] = cr1;
    }
}

// ---- t1 gather: list-driven over r1 rows, dense slabs, float4/thread ----
__global__ void gather_t1(const float* __restrict__ h1, float* __restrict__ t1,
                          const int* __restrict__ w_cnt, const int2* __restrict__ w_pairsD,
                          const int* __restrict__ r1list, const int* __restrict__ r1tail) {
    int total = (*r1tail) * 32;            // 8 float4 lanes x B=4 per row
    int gstride = gridDim.x * blockDim.x;
    for (int idx = blockIdx.x * blockDim.x + threadIdx.x; idx < total; idx += gstride) {
        int row = r1list[idx >> 5];
        int rem = idx & 31;
        int c4 = rem & 7;
        int b = rem >> 3;
        int L = w_cnt[row]; if (L > WDEG) L = WDEG;
        const int2* pr = w_pairsD + (size_t)row * WDEG;
        const float4* sb = (const float4*)h1 + b * 8 + c4;
        float4 acc = make_float4(0.f, 0.f, 0.f, 0.f);
        int i = 0;
        int L4 = L & ~3;
        for (; i < L4; i += 4) {
            int2 p0 = pr[i + 0];
            int2 p1 = pr[i + 1];
            int2 p2 = pr[i + 2];
            int2 p3 = pr[i + 3];
            float4 s0 = sb[(size_t)p0.x * 32];
            float4 s1 = sb[(size_t)p1.x * 32];
            float4 s2 = sb[(size_t)p2.x * 32];
            float4 s3 = sb[(size_t)p3.x * 32];
            float v0 = __int_as_float(p0.y), v1 = __int_as_float(p1.y);
            float v2 = __int_as_float(p2.y), v3 = __int_as_float(p3.y);
            acc.x += v0 * s0.x + v1 * s1.x + v2 * s2.x + v3 * s3.x;
            acc.y += v0 * s0.y + v1 * s1.y + v2 * s2.y + v3 * s3.y;
            acc.z += v0 * s0.z + v1 * s1.z + v2 * s2.z + v3 * s3.z;
            acc.w += v0 * s0.w + v1 * s1.w + v2 * s2.w + v3 * s3.w;
        }
        for (; i < L; ++i) {
            int2 p = pr[i];
            float4 sv = sb[(size_t)p.x * 32];
            float v = __int_as_float(p.y);
            acc.x += v * sv.x; acc.y += v * sv.y; acc.z += v * sv.z; acc.w += v * sv.w;
        }
        ((float4*)t1)[(size_t)row * 32 + b * 8 + c4] = acc;
    }
}

// ---- fused x1 gather + gemm2: per n1 node, 32 threads; x1 stays in LDS ----
__global__ void x1gemm2(const float* __restrict__ t1, const float* __restrict__ W2,
                        const float* __restrict__ diag1, float* __restrict__ h2,
                        const int* __restrict__ n1list, const int* __restrict__ wi_cnt,
                        const int2* __restrict__ wi_pairsD,
                        const int* __restrict__ n1tail) {
    __shared__ float sW[32 * 16];
    __shared__ float xls[8][128];            // 8 rows/block x [B][32]
    for (int i = threadIdx.x; i < 512; i += blockDim.x) sW[i] = W2[i];
    int n1c = *n1tail; if (n1c > N1_CAP) n1c = N1_CAP;
    int g = threadIdx.x >> 5;                // row group 0..7
    int t32 = threadIdx.x & 31;
    int b = t32 >> 3, c4 = t32 & 7;
    for (int base = blockIdx.x * 8; base < n1c; base += gridDim.x * 8) {
        int s = base + g;
        bool active = (s < n1c);
        int n = 0;
        if (active) {
            n = n1list[s];
            int L = wi_cnt[n]; if (L > WIDEG) L = WIDEG;
            const int2* pr = wi_pairsD + (size_t)n * WIDEG;
            const float4* sb = (const float4*)t1 + b * 8 + c4;
            float4 acc = make_float4(0.f, 0.f, 0.f, 0.f);
            int i = 0;
            int L2 = L & ~1;
            for (; i < L2; i += 2) {
                int2 p0 = pr[i + 0];
                int2 p1 = pr[i + 1];
                float4 s0 = sb[(size_t)p0.x * 32];
                float4 s1 = sb[(size_t)p1.x * 32];
                float v0 = __int_as_float(p0.y) * diag1[p0.x];
                float v1 = __int_as_float(p1.y) * diag1[p1.x];
                acc.x += v0 * s0.x + v1 * s1.x;
                acc.y += v0 * s0.y + v1 * s1.y;
                acc.z += v0 * s0.z + v1 * s1.z;
                acc.w += v0 * s0.w + v1 * s1.w;
            }
            if (i < L) {
                int2 p = pr[i];
                float4 sv = sb[(size_t)p.x * 32];
                float v = __int_as_float(p.y) * diag1[p.x];
                acc.x += v * sv.x; acc.y += v * sv.y; acc.z += v * sv.z; acc.w += v * sv.w;
            }
            float* xp = &xls[g][b * 32 + c4 * 4];
            xp[0] = acc.x > 0.f ? acc.x : NEG_SLOPE * acc.x;
            xp[1] = acc.y > 0.f ? acc.y : NEG_SLOPE * acc.y;
            xp[2] = acc.z > 0.f ? acc.z : NEG_SLOPE * acc.z;
            xp[3] = acc.w > 0.f ? acc.w : NEG_SLOPE * acc.w;
        }
        __syncthreads();
        if (active) {
#pragma unroll
            for (int half = 0; half < 2; ++half) {
                int o = t32 + half * 32;
                int bb = o >> 4, cc = o & 15;
                const float* xp = &xls[g][bb * 32];
                float acc = 0.f;
#pragma unroll
                for (int k = 0; k < 32; ++k) acc += xp[k] * sW[k * 16 + cc];
                h2[(size_t)n * 64 + o] = acc;
            }
        }
        __syncthreads();
    }
}

// ---- t2 gather + x2 accumulation + heads, ONE block of 1024 threads ----
__global__ void t2x2heads(const float* __restrict__ h2,
                          const int* __restrict__ w_cnt, const int2* __restrict__ w_pairsD,
                          const int* __restrict__ r2list, const int* __restrict__ r2tail,
                          float* __restrict__ t2,
                          const int2* __restrict__ x2list, const int* __restrict__ x2tail,
                          const float* __restrict__ diag2,
                          const float* __restrict__ rw1, const float* __restrict__ rb1,
                          const float* __restrict__ rw2, const float* __restrict__ rb2,
                          float* __restrict__ out) {
    int r2c = *r2tail; if (r2c > R2_CAP) r2c = R2_CAP;
    for (int idx = threadIdx.x; idx < r2c * 16; idx += blockDim.x) {
        int row = r2list[idx >> 4];
        int rem = idx & 15;
        int c4 = rem & 3;
        int b = rem >> 2;
        int L = w_cnt[row]; if (L > WDEG) L = WDEG;
        const int2* pr = w_pairsD + (size_t)row * WDEG;
        const float4* sb = (const float4*)h2 + b * 4 + c4;
        float4 acc = make_float4(0.f, 0.f, 0.f, 0.f);
        for (int i = 0; i < L; ++i) {
            int2 p = pr[i];
            float4 sv = sb[(size_t)p.x * 16];
            float v = __int_as_float(p.y);
            acc.x += v * sv.x; acc.y += v * sv.y; acc.z += v * sv.z; acc.w += v * sv.w;
        }
        ((float4*)t2)[(size_t)row * 16 + b * 4 + c4] = acc;
    }
    __syncthreads();

    int cnt = *x2tail; if (cnt > X2_CAP) cnt = X2_CAP;
    int g = threadIdx.x >> 6, l = threadIdx.x & 63;
    int b = l >> 4, c = l & 15;
    float a0 = 0.f, a1 = 0.f;
    for (int i = g; i < cnt; i += 16) {
        int2 rec = x2list[i];
        int col = rec.x >> 1;
        float coef = __int_as_float(rec.y) * diag2[col];
        float v = t2[(size_t)col * 64 + b * 16 + c] * coef;
        if (rec.x & 1) a1 += v; else a0 += v;
    }
    __shared__ float red0[16][64], red1[16][64], xs[2][64];
    red0[g][l] = a0; red1[g][l] = a1;
    __syncthreads();
    if (threadIdx.x < 64) {
        float s0 = 0.f, s1 = 0.f;
#pragma unroll
        for (int gg = 0; gg < 16; ++gg) { s0 += red0[gg][l]; s1 += red1[gg][l]; }
        xs[0][l] = s0; xs[1][l] = s1;
    }
    __syncthreads();
    if (threadIdx.x < 8) {
        int bb = threadIdx.x >> 1, which = threadIdx.x & 1;
        const float* w = which ? rw2 : rw1;
        float acc = which ? rb2[0] : rb1[0];
        for (int k = 0; k < 16; ++k) {
            float xv = xs[which][bb * 16 + k];
            xv = xv > 0.f ? xv : NEG_SLOPE * xv;
            acc += xv * w[k];
        }
        out[bb * 2 + which] = acc;
    }
}

extern "C" void kernel_launch(void* const* d_in, const int* in_sizes, int n_in,
                              void* d_out, int out_size, void* d_ws, size_t ws_size,
                              hipStream_t stream) {
    const int*   w_rows  = (const int*)d_in[0];
    const int*   w_cols  = ((const int*)d_in[0]) + E;
    const float* w_val   = (const float*)d_in[1];
    const int*   wi_rows = (const int*)d_in[2];
    const int*   wi_cols = ((const int*)d_in[2]) + E;
    const float* wi_val  = (const float*)d_in[3];
    const float* x       = (const float*)d_in[4];
    const float* W1      = (const float*)d_in[5];
    const float* diag1   = (const float*)d_in[6];
    const float* W2      = (const float*)d_in[7];
    const float* diag2   = (const float*)d_in[8];
    const float* rw1     = (const float*)d_in[9];
    const float* rb1     = (const float*)d_in[10];
    const float* rw2     = (const float*)d_in[11];
    const float* rb2     = (const float*)d_in[12];
    float* out = (float*)d_out;

    // ---------------- workspace layout (~174 MB of ~268 MB) ----------------
    float* h1 = (float*)d_ws;                    // [N][B][32] (25.6 MB)
    float* t1 = h1 + (size_t)B * N * 32;         // [R][B][32] (51.2 MB); t2 aliases
    float* h2 = t1 + (size_t)B * R * 32;         // [N][B][16] (12.8 MB)
    int* ip = (int*)(h2 + (size_t)B * N * 16);
    // zeroed block (contiguous):
    int* w_cnt  = ip; ip += R;
    int* wi_cnt = ip; ip += N;
    size_t zero_words = (size_t)(ip - w_cnt);
    // un-zeroed (frontier writes tails explicitly):
    int* tails  = ip; ip += 8;     // [0]=x2 [1]=r2 [2]=n1 [3]=r1
    int* r2list = ip; ip += R2_CAP;
    int* n1list = ip; ip += N1_CAP;
    int* r1list = ip; ip += R;
    int2* x2list = (int2*)ip; ip += 2 * X2_CAP;
    int2* w_pairsD  = (int2*)ip; ip += 2 * (size_t)R * WDEG;    // 51.2 MB
    int2* wi_pairsD = (int2*)ip; ip += 2 * (size_t)N * WIDEG;   // 32 MB

    float* t2 = t1;                              // alias: t1 dead before t2 written

    const int blk = 256;
    const int e4 = E / 4;
    const int G1 = (N * B + blk - 1) / blk;         // gemm1 blocks (782)
    const int Gs = (e4 + 511) / 512;                // slab-build blocks (782)

    (void)hipMemsetAsync(w_cnt, 0, zero_words * sizeof(int), stream);

    // 1) gemm1 + full dense-slab CSR build for both matrices (one dispatch)
    build_all<<<G1 + Gs, blk, 0, stream>>>(
        x, W1, h1,
        (const int4*)w_rows, (const int4*)w_cols, (const float4*)w_val,
        (const int4*)wi_rows, (const int4*)wi_cols, (const float4*)wi_val,
        w_cnt, w_pairsD, wi_cnt, wi_pairsD, e4, G1);

    // 2) backward slice: one block, LDS bitmask dedup, 3 levels
    frontier<<<1, 1024, 0, stream>>>(w_cnt, w_pairsD, wi_cnt, wi_pairsD,
                                     x2list, r2list, n1list, r1list, tails);

    // 3) t1 gather over r1 rows
    gather_t1<<<4096, blk, 0, stream>>>(h1, t1, w_cnt, w_pairsD, r1list, tails + 3);

    // 4) fused x1 gather (diag1 here) + gemm2 over n1 nodes
    x1gemm2<<<256, blk, 0, stream>>>(t1, W2, diag1, h2, n1list, wi_cnt, wi_pairsD,
                                     tails + 2);

    // 5) t2 gather + x2 + heads, single block
    t2x2heads<<<1, 1024, 0, stream>>>(h2, w_cnt, w_pairsD, r2list, tails + 1,
                                      t2, x2list, tails + 0, diag2,
                                      rw1, rb1, rw2, rb2, out);
}

// Round 12
// 291.957 us; speedup vs baseline: 1.4288x; 1.4288x over previous
//
#include <hip/hip_runtime.h>

#define NEG_SLOPE 0.2f

static const int B = 4, N = 50000, R = 100000, E = 1600000;
static const int WDEG  = 64;      // dense w-CSR slab per R-row (mean deg 16)
static const int WIDEG = 96;      // dense wi-CSR slab per n1-slot (mean deg 32)
static const int R2_CAP = 1024;   // distinct t2 rows (expected ~64)
static const int N1_CAP = 4096;   // n1 nodes (expected ~1k)
static const int X2_CAP = 2048;   // x2 edges (expected ~64)
static const int I4PB = 512;      // int4 groups per scan block (2048 edges)

// flagsR bits: 1 = R2 (rows needed for t2), 2 = R1 (rows needed for t1)

// ---------- fusedA: blocks [0,G1) = gemm1 (x->h1), blocks [G1,..) = markA ----------
__global__ void fusedA(const float* __restrict__ x, const float* __restrict__ W1,
                       float* __restrict__ h1,
                       const int4* __restrict__ wi_rows4, const int* __restrict__ wi_cols,
                       const float* __restrict__ wi_val,
                       int* __restrict__ flagsR, int2* __restrict__ x2list,
                       int* __restrict__ x2tail, int* __restrict__ r2list,
                       int* __restrict__ r2tail, int e4, int G1) {
    if ((int)blockIdx.x < G1) {
        __shared__ float sW[32 * 32];
        for (int i = threadIdx.x; i < 1024; i += blockDim.x) sW[i] = W1[i];
        __syncthreads();
        int id = blockIdx.x * blockDim.x + threadIdx.x;
        if (id >= N * B) return;
        int n = id >> 2, b = id & 3;
        const float* xr = x + ((size_t)b * N + n) * 32;
        float acc[32];
#pragma unroll
        for (int c = 0; c < 32; ++c) acc[c] = 0.f;
#pragma unroll
        for (int k = 0; k < 32; ++k) {
            float xv = xr[k];
#pragma unroll
            for (int c = 0; c < 32; ++c) acc[c] += xv * sW[k * 32 + c];
        }
        float* o = h1 + ((size_t)n * B + b) * 32;
#pragma unroll
        for (int c = 0; c < 32; ++c) o[c] = acc[c];
    } else {
        int blk = blockIdx.x - G1;
        int base = blk * (blockDim.x * 4) + threadIdx.x;
#pragma unroll
        for (int k = 0; k < 4; ++k) {
            int i = base + k * blockDim.x;
            if (i >= e4) continue;
            int4 r = wi_rows4[i];
            int rr[4] = {r.x, r.y, r.z, r.w};
#pragma unroll
            for (int j = 0; j < 4; ++j) {
                if (rr[j] >= N - 2) {
                    int ed = i * 4 + j;
                    int col = wi_cols[ed];
                    int old = atomicOr(&flagsR[col], 1);
                    if (!(old & 1)) {
                        int p = atomicAdd(r2tail, 1);
                        if (p < R2_CAP) r2list[p] = col;
                    }
                    int pos = atomicAdd(x2tail, 1);   // ~64 total: negligible
                    if (pos < X2_CAP)
                        x2list[pos] = make_int2(col * 2 + (rr[j] - (N - 2)),
                                                __float_as_int(wi_val[ed]));
                }
            }
        }
    }
}

// ---- markB: w edges with flagged row -> flagN1[col], n1list append + slot map ----
__global__ void markB(const int4* __restrict__ w_rows4, const int* __restrict__ w_cols,
                      const int* __restrict__ flagsR, int* __restrict__ flagN1,
                      int* __restrict__ n1list, int* __restrict__ n1slot,
                      int* __restrict__ n1tail, int e4) {
    __shared__ int lcount, gbase;
    __shared__ int sbuf[2048];
    if (threadIdx.x == 0) lcount = 0;
    __syncthreads();
    int lane = threadIdx.x & 63;
#pragma unroll
    for (int k = 0; k < 2; ++k) {
        int i = blockIdx.x * I4PB + k * 256 + threadIdx.x;
        int4 r = make_int4(-1, -1, -1, -1);
        if (i < e4) r = w_rows4[i];
        int rr[4] = {r.x, r.y, r.z, r.w};
#pragma unroll
        for (int j = 0; j < 4; ++j) {
            bool isnew = false;
            int c = 0;
            if (rr[j] >= 0 && flagsR[rr[j]] != 0) {
                c = w_cols[i * 4 + j];
                int old = atomicOr(&flagN1[c], 1);
                isnew = (old == 0);
            }
            unsigned long long m = __ballot(isnew);
            if (m) {
                int leader = __ffsll(m) - 1;
                int b0 = 0;
                if (lane == leader) b0 = atomicAdd(&lcount, __popcll(m));
                b0 = __shfl(b0, leader);
                if (isnew) sbuf[b0 + __popcll(m & ((1ull << lane) - 1))] = c;
            }
        }
    }
    __syncthreads();
    if (threadIdx.x == 0) gbase = atomicAdd(n1tail, lcount);
    __syncthreads();
    for (int t = threadIdx.x; t < lcount; t += blockDim.x) {
        int n = sbuf[t];
        int slot = gbase + t;
        if (slot < N1_CAP) { n1list[slot] = n; n1slot[n] = slot; }
    }
}

// ---- markC: wi edges with flagN1 row -> flagsR bit2 + gated wi-slab placement ----
__global__ void markC_wi(const int4* __restrict__ wi_rows4, const int* __restrict__ wi_cols,
                         const float* __restrict__ wi_val, const float* __restrict__ diag1,
                         const int* __restrict__ flagN1, const int* __restrict__ n1slot,
                         int* __restrict__ flagsR, int* __restrict__ wi_cnt,
                         int2* __restrict__ wi_pairsD, int e4) {
    int base = blockIdx.x * I4PB + threadIdx.x;
#pragma unroll
    for (int k = 0; k < 2; ++k) {
        int i = base + k * 256;
        if (i >= e4) continue;
        int4 r = wi_rows4[i];
        int rr[4] = {r.x, r.y, r.z, r.w};
#pragma unroll
        for (int j = 0; j < 4; ++j) {
            int row = rr[j];
            if (flagN1[row] != 0) {
                int ed = i * 4 + j;
                int col = wi_cols[ed];
                float cf = wi_val[ed] * diag1[col];
                int slot = n1slot[row];
                int pos = atomicAdd(&wi_cnt[row], 1);
                if (slot < N1_CAP && pos < WIDEG)
                    wi_pairsD[(size_t)slot * WIDEG + pos] =
                        make_int2(col, __float_as_int(cf));
                atomicOr(&flagsR[col], 2);
            }
        }
    }
}

// ---- wplace: w edges with flagsR row -> gated dense slab write + count ----
__global__ void wplace(const int4* __restrict__ w_rows4, const int* __restrict__ w_cols,
                       const float* __restrict__ w_val, const int* __restrict__ flagsR,
                       int* __restrict__ w_cnt, int2* __restrict__ w_pairsD, int e4) {
    int base = blockIdx.x * I4PB + threadIdx.x;
#pragma unroll
    for (int k = 0; k < 2; ++k) {
        int i = base + k * 256;
        if (i >= e4) continue;
        int4 r = w_rows4[i];
        int rr[4] = {r.x, r.y, r.z, r.w};
#pragma unroll
        for (int j = 0; j < 4; ++j) {
            int row = rr[j];
            if (flagsR[row] != 0) {
                int ed = i * 4 + j;
                int pos = atomicAdd(&w_cnt[row], 1);
                if (pos < WDEG)
                    w_pairsD[(size_t)row * WDEG + pos] =
                        make_int2(w_cols[ed], __float_as_int(w_val[ed]));
            }
        }
    }
}

// ---- x1fused: per n1 node, t1 computed on-the-fly (no t1 buffer), then gemm2 ----
// 128 threads/node: 4 subgroups x 32 lanes split the wi-edges; LDS reduce; gemm2.
__global__ __launch_bounds__(256)
void x1fused(const float* __restrict__ h1, const float* __restrict__ W2,
             float* __restrict__ h2,
             const int* __restrict__ n1list, const int* __restrict__ wi_cnt,
             const int2* __restrict__ wi_pairsD,
             const int* __restrict__ w_cnt, const int2* __restrict__ w_pairsD,
             const int* __restrict__ n1tail) {
    __shared__ float sW[512];
    __shared__ float xpart[2][4][128];
    for (int i = threadIdx.x; i < 512; i += 256) sW[i] = W2[i];
    int n1c = *n1tail; if (n1c > N1_CAP) n1c = N1_CAP;
    int g2 = threadIdx.x >> 7;               // node within block (0..1)
    int sub = (threadIdx.x >> 5) & 3;        // wi-edge subgroup (0..3)
    int t32 = threadIdx.x & 31;
    int b = t32 >> 3, c4 = t32 & 7;
    __syncthreads();
    for (int base = blockIdx.x * 2; base < n1c; base += gridDim.x * 2) {
        int s = base + g2;
        bool active = (s < n1c);
        int n = 0;
        float4 acc = make_float4(0.f, 0.f, 0.f, 0.f);
        if (active) {
            n = n1list[s];
            int L = wi_cnt[n]; if (L > WIDEG) L = WIDEG;
            const int2* pr = wi_pairsD + (size_t)s * WIDEG;
            const float4* hb = (const float4*)h1 + b * 8 + c4;
            for (int e = sub; e < L; e += 4) {
                int2 p = pr[e];
                float cf = __int_as_float(p.y);
                int col = p.x;
                int Lw = w_cnt[col]; if (Lw > WDEG) Lw = WDEG;
                const int2* pw = w_pairsD + (size_t)col * WDEG;
                float4 t = make_float4(0.f, 0.f, 0.f, 0.f);
                int i = 0;
                int Lw2 = Lw & ~1;
                for (; i < Lw2; i += 2) {
                    int2 q0 = pw[i], q1 = pw[i + 1];
                    float4 s0 = hb[(size_t)q0.x * 32];
                    float4 s1 = hb[(size_t)q1.x * 32];
                    float v0 = __int_as_float(q0.y), v1 = __int_as_float(q1.y);
                    t.x += v0 * s0.x + v1 * s1.x;
                    t.y += v0 * s0.y + v1 * s1.y;
                    t.z += v0 * s0.z + v1 * s1.z;
                    t.w += v0 * s0.w + v1 * s1.w;
                }
                if (i < Lw) {
                    int2 q = pw[i];
                    float4 s0 = hb[(size_t)q.x * 32];
                    float v = __int_as_float(q.y);
                    t.x += v * s0.x; t.y += v * s0.y; t.z += v * s0.z; t.w += v * s0.w;
                }
                acc.x += cf * t.x; acc.y += cf * t.y;
                acc.z += cf * t.z; acc.w += cf * t.w;
            }
        }
        float* xp = &xpart[g2][sub][b * 32 + c4 * 4];
        xp[0] = acc.x; xp[1] = acc.y; xp[2] = acc.z; xp[3] = acc.w;
        __syncthreads();
        int tid128 = threadIdx.x & 127;
        if (active && tid128 < 64) {          // 64 outputs per node: o = bb*16+cc
            int bb = tid128 >> 4, cc = tid128 & 15;
            float accum = 0.f;
#pragma unroll
            for (int k = 0; k < 32; ++k) {
                float xv = xpart[g2][0][bb * 32 + k] + xpart[g2][1][bb * 32 + k]
                         + xpart[g2][2][bb * 32 + k] + xpart[g2][3][bb * 32 + k];
                xv = xv > 0.f ? xv : NEG_SLOPE * xv;   // lrelu(x1) feeds gemm2
                accum += xv * sW[k * 16 + cc];
            }
            h2[(size_t)n * 64 + tid128] = accum;
        }
        __syncthreads();
    }
}

// ---- t2 gather + x2 accumulation + heads, ONE block of 1024 threads ----
__global__ void t2x2heads(const float* __restrict__ h2,
                          const int* __restrict__ w_cnt, const int2* __restrict__ w_pairsD,
                          const int* __restrict__ r2list, const int* __restrict__ r2tail,
                          float* __restrict__ t2,
                          const int2* __restrict__ x2list, const int* __restrict__ x2tail,
                          const float* __restrict__ diag2,
                          const float* __restrict__ rw1, const float* __restrict__ rb1,
                          const float* __restrict__ rw2, const float* __restrict__ rb2,
                          float* __restrict__ out) {
    int r2c = *r2tail; if (r2c > R2_CAP) r2c = R2_CAP;
    for (int idx = threadIdx.x; idx < r2c * 16; idx += blockDim.x) {
        int row = r2list[idx >> 4];
        int rem = idx & 15;
        int c4 = rem & 3;
        int b = rem >> 2;
        int L = w_cnt[row]; if (L > WDEG) L = WDEG;
        const int2* pr = w_pairsD + (size_t)row * WDEG;
        const float4* sb = (const float4*)h2 + b * 4 + c4;
        float4 acc = make_float4(0.f, 0.f, 0.f, 0.f);
        for (int i = 0; i < L; ++i) {
            int2 p = pr[i];
            float4 sv = sb[(size_t)p.x * 16];
            float v = __int_as_float(p.y);
            acc.x += v * sv.x; acc.y += v * sv.y; acc.z += v * sv.z; acc.w += v * sv.w;
        }
        ((float4*)t2)[(size_t)row * 16 + b * 4 + c4] = acc;
    }
    __syncthreads();

    int cnt = *x2tail; if (cnt > X2_CAP) cnt = X2_CAP;
    int g = threadIdx.x >> 6, l = threadIdx.x & 63;
    int b = l >> 4, c = l & 15;
    float a0 = 0.f, a1 = 0.f;
    for (int i = g; i < cnt; i += 16) {
        int2 rec = x2list[i];
        int col = rec.x >> 1;
        float coef = __int_as_float(rec.y) * diag2[col];
        float v = t2[(size_t)col * 64 + b * 16 + c] * coef;
        if (rec.x & 1) a1 += v; else a0 += v;
    }
    __shared__ float red0[16][64], red1[16][64], xs[2][64];
    red0[g][l] = a0; red1[g][l] = a1;
    __syncthreads();
    if (threadIdx.x < 64) {
        float s0 = 0.f, s1 = 0.f;
#pragma unroll
        for (int gg = 0; gg < 16; ++gg) { s0 += red0[gg][l]; s1 += red1[gg][l]; }
        xs[0][l] = s0; xs[1][l] = s1;
    }
    __syncthreads();
    if (threadIdx.x < 8) {
        int bb = threadIdx.x >> 1, which = threadIdx.x & 1;
        const float* w = which ? rw2 : rw1;
        float acc = which ? rb2[0] : rb1[0];
        for (int k = 0; k < 16; ++k) {
            float xv = xs[which][bb * 16 + k];
            xv = xv > 0.f ? xv : NEG_SLOPE * xv;
            acc += xv * w[k];
        }
        out[bb * 2 + which] = acc;
    }
}

extern "C" void kernel_launch(void* const* d_in, const int* in_sizes, int n_in,
                              void* d_out, int out_size, void* d_ws, size_t ws_size,
                              hipStream_t stream) {
    const int*   w_rows  = (const int*)d_in[0];
    const int*   w_cols  = ((const int*)d_in[0]) + E;
    const float* w_val   = (const float*)d_in[1];
    const int*   wi_rows = (const int*)d_in[2];
    const int*   wi_cols = ((const int*)d_in[2]) + E;
    const float* wi_val  = (const float*)d_in[3];
    const float* x       = (const float*)d_in[4];
    const float* W1      = (const float*)d_in[5];
    const float* diag1   = (const float*)d_in[6];
    const float* W2      = (const float*)d_in[7];
    const float* diag2   = (const float*)d_in[8];
    const float* rw1     = (const float*)d_in[9];
    const float* rb1     = (const float*)d_in[10];
    const float* rw2     = (const float*)d_in[11];
    const float* rb2     = (const float*)d_in[12];
    float* out = (float*)d_out;

    // ---------------- workspace layout (~120 MB) ----------------
    float* h1 = (float*)d_ws;                    // [n][B][32] (25.6 MB)
    float* h2 = h1 + (size_t)B * N * 32;         // [n][64]    (12.8 MB)
    float* t2 = h2 + (size_t)N * 64;             // [r][64]    (25.6 MB)
    int* ip = (int*)(t2 + (size_t)R * 64);
    // zeroed block (contiguous):
    int* w_cnt  = ip; ip += R;
    int* wi_cnt = ip; ip += N;
    int* flagsR = ip; ip += R;
    int* flagN1 = ip; ip += N;
    int* tails  = ip; ip += 8;    // [0]=x2 [1]=r2 [2]=n1
    size_t zero_words = (size_t)(ip - w_cnt);
    // un-zeroed:
    int* n1slot = ip; ip += N;
    int* n1list = ip; ip += N1_CAP;
    int* r2list = ip; ip += R2_CAP;
    int2* x2list = (int2*)ip; ip += 2 * X2_CAP;
    int2* w_pairsD  = (int2*)ip; ip += 2 * (size_t)R * WDEG;       // 51.2 MB
    int2* wi_pairsD = (int2*)ip; ip += 2 * (size_t)N1_CAP * WIDEG; // 3.1 MB

    const int blk = 256;
    const int e4 = E / 4;
    const int G1 = (N * B + blk - 1) / blk;            // gemm1 blocks
    const int G2 = (e4 + blk * 4 - 1) / (blk * 4);     // markA blocks
    const int stageGrid = (e4 + I4PB - 1) / I4PB;

    (void)hipMemsetAsync(w_cnt, 0, zero_words * sizeof(int), stream);

    // 1) gemm1 + markA fused
    fusedA<<<G1 + G2, blk, 0, stream>>>(x, W1, h1, (const int4*)wi_rows, wi_cols, wi_val,
                                        flagsR, x2list, tails + 0, r2list, tails + 1,
                                        e4, G1);
    // 2) markB: flagN1 + n1list/slot
    markB<<<stageGrid, blk, 0, stream>>>((const int4*)w_rows, w_cols, flagsR, flagN1,
                                         n1list, n1slot, tails + 2, e4);
    // 3) markC: flagsR bit2 + gated wi-slab placement (diag1 folded)
    markC_wi<<<stageGrid, blk, 0, stream>>>((const int4*)wi_rows, wi_cols, wi_val, diag1,
                                            flagN1, n1slot, flagsR, wi_cnt, wi_pairsD, e4);
    // 4) gated w placement into dense slabs
    wplace<<<stageGrid, blk, 0, stream>>>((const int4*)w_rows, w_cols, w_val, flagsR,
                                          w_cnt, w_pairsD, e4);
    // 5) fused on-the-fly t1 + x1 + gemm2 (no t1 buffer)
    x1fused<<<512, blk, 0, stream>>>(h1, W2, h2, n1list, wi_cnt, wi_pairsD,
                                     w_cnt, w_pairsD, tails + 2);
    // 6) t2 gather + x2 + heads, single block
    t2x2heads<<<1, 1024, 0, stream>>>(h2, w_cnt, w_pairsD, r2list, tails + 1,
                                      t2, x2list, tails + 0, diag2,
                                      rw1, rb1, rw2, rb2, out);
}